// Round 10
// baseline (413.789 us; speedup 1.0000x reference)
//
#include <hip/hip_runtime.h>

#define H    128
#define T    512
#define DX   4
#define BB   220
#define SAMP 10
#define NS   (BB*SAMP)
#define M    4        // sequences per block (220 = 55*4, no tail)
#define NBLK 55       // 220/4
#define MAXSLOT 84    // max watcher slots per block (e==0: M*21)

typedef _Float16 half8 __attribute__((ext_vector_type(8)));
typedef float    f32x4 __attribute__((ext_vector_type(4)));

// workspace layout (fp32 elements)
#define WS_TEMB 0
#define WS_AEMB (WS_TEMB + BB*H)
#define WS_FEMB (WS_AEMB + BB*H)
#define WS_TA   (WS_FEMB + BB*H)
#define WS_TF   (WS_TA + NS*H)
#define WS_AN   (WS_TF + NS*H)
#define WS_FA   (WS_AN + NS*H)
#define WS_FLAGS (WS_FA + NS*H)   // 2 ints: [0]=floats-are-bf16, [1]=ints-are-int64

#define LOG2E  1.442695041f
#define LOG2E2 2.885390082f

__device__ static inline float bf2f(unsigned short u) {
  unsigned int i = ((unsigned int)u) << 16;
  return __builtin_bit_cast(float, i);
}
__device__ static inline unsigned short f2bf(float f) {
  unsigned int i = __builtin_bit_cast(unsigned int, f);
  i += 0x7fffu + ((i >> 16) & 1u);
  return (unsigned short)(i >> 16);
}
__device__ static inline float loadF(const void* p, size_t i, int isbf) {
  return isbf ? bf2f(((const unsigned short*)p)[i]) : ((const float*)p)[i];
}
__device__ static inline int loadI(const void* p, int i, int is64) {
  return is64 ? (int)((const unsigned int*)p)[2*(size_t)i] : ((const int*)p)[i];
}
__device__ static inline float frcp(float x) { return __builtin_amdgcn_rcpf(x); }
__device__ static inline float ex2(float x)  { return __builtin_amdgcn_exp2f(x); }
// args pre-scaled by log2e (sigm) / 2*log2e (tanh)
__device__ static inline float sigmY(float y)  { return frcp(1.f + ex2(-y)); }
__device__ static inline float tanhY(float y)  { return 1.f - 2.f*frcp(1.f + ex2(y)); }
__device__ static inline float scrub(float x) { return (x == x) ? x : 0.f; }
__device__ static inline int clampT(int v) { v = v - 1; if (v < 0) v = 0; if (v > T-1) v = T-1; return v; }
// A rows 4-15 duplicate rows 0-3 => G[r] = gate[seq r][col] in every quad
__device__ static inline float qsel(f32x4 G, int quad) {
  float g01 = (quad & 1) ? G[1] : G[0];
  float g23 = (quad & 1) ? G[3] : G[2];
  return (quad & 2) ? g23 : g01;
}

__global__ __launch_bounds__(512, 2) void lstm_scan(
    const void* __restrict__ x0_, const void* __restrict__ len0,
    const void* __restrict__ sub_ta, const void* __restrict__ sub_tf,
    const void* __restrict__ x1_, const void* __restrict__ len1,
    const void* __restrict__ sub_an,
    const void* __restrict__ x2_, const void* __restrict__ len2,
    const void* __restrict__ sub_fa,
    const void* __restrict__ Wih, const void* __restrict__ Whh,
    const void* __restrict__ bih, const void* __restrict__ bhh,
    float* __restrict__ ws)
{
  const int e      = blockIdx.y;
  const int s0     = blockIdx.x * M;
  const int tid    = threadIdx.x;
  const int lane   = tid & 63;
  const int w      = tid >> 6;     // wave 0..7, owns h-cols [16w,16w+16)
  const int lo     = lane & 15;
  const int quad   = lane >> 4;    // elementwise: my seq

  // ---- in-block dtype detection (uniform scalar loop; block (0,0) publishes for dists)
  int fbf, f64;
  {
    const unsigned int* wp = (const unsigned int*)Whh;
    int cnt = 0;
    for (int i = 0; i < 64; ++i) {
      unsigned int lo16 = wp[i] & 0xFFFFu;
      int ex = (int)((lo16 >> 7) & 0xFFu);
      cnt += (ex >= 100 && ex <= 130);
    }
    fbf = (cnt >= 40);
    const unsigned int* l = (const unsigned int*)len0;
    f64 = ((l[1] | l[3] | l[5] | l[7]) == 0u);
    if (blockIdx.x == 0 && blockIdx.y == 0 && tid == 0) {
      int* fo = (int*)(ws + WS_FLAGS); fo[0] = fbf; fo[1] = f64;
    }
  }

  const void* xin  = (e==0) ? x0_ : (e==1 ? x1_ : x2_);
  const void* lenp = (e==0) ? len0 : (e==1 ? len1 : len2);

  // h'(t) in MFMA-fragment-major order: [buf][ktile][chunk=quad'*4+seq][8 halves]
  __shared__ __align__(16) _Float16 afr[2][4][16][8];
  __shared__ __align__(16) float2 xbf[T][4];              // x pairs, [t][seq]: 32B/t
  __shared__ __align__(16) _Float16 sbuf[MAXSLOT][H];     // watcher snapshots (f16)
  __shared__ int slot_off[MAXSLOT];                       // ws offset per slot

  ((unsigned int*)afr)[tid] = 0u;                         // zero both h buffers
  // ---- stage x[:, :, 0:2] to LDS as f32 pairs, [t][seq] layout
  for (int i = tid; i < M*T; i += 512) {
    int t = i >> 2, m = i & 3;
    size_t base = ((size_t)(s0+m)*T + t) * DX;
    xbf[t][m] = make_float2(loadF(xin, base + 0, fbf), loadF(xin, base + 1, fbf));
  }
  // ---- weight B-fragments: W_hh only, K=128; pre-scaled (i,f,o: log2e; g: 2*log2e)
  half8 Bf[4][4];
  const int col = w*16 + lo;
  #pragma unroll
  for (int q = 0; q < 4; ++q) {
    const float sc = (q == 2) ? LOG2E2 : LOG2E;
    const int g = q*128 + col;
    #pragma unroll
    for (int kt = 0; kt < 4; ++kt) {
      #pragma unroll
      for (int j = 0; j < 8; ++j) {
        const int k = kt*32 + quad*8 + j;
        Bf[q][kt][j] = (_Float16)(sc * loadF(Whh, (size_t)g*H + k, fbf));
      }
    }
  }
  // ---- per-lane x-weights and bias (per gate, col-dependent only)
  float wx0[4], wx1[4], bb[4];
  #pragma unroll
  for (int q = 0; q < 4; ++q) {
    const float sc = (q == 2) ? LOG2E2 : LOG2E;
    const int g = q*128 + col;
    wx0[q] = sc * loadF(Wih, (size_t)g*2 + 0, fbf);
    wx1[q] = sc * loadF(Wih, (size_t)g*2 + 1, fbf);
    bb[q]  = sc * (loadF(bih, g, fbf) + loadF(bhh, g, fbf));
  }
  // ---- per-thread watcher slot (slot id == tid; max 84 < 512)
  const int nslots = (e == 0) ? M*21 : M*11;
  int myt = -1, mym = 0;
  if (e == 0) {
    if (tid < M*21) {
      int m = tid / 21, j = tid - m*21, sg = s0 + m;
      mym = m;
      int off;
      if (j == 0)       { myt = clampT(loadI(lenp, sg, f64));            off = WS_TEMB + sg*H; }
      else if (j <= 10) { int k = sg*10 + (j-1);  myt = clampT(loadI(sub_ta, k, f64)); off = WS_TA + k*H; }
      else              { int k = sg*10 + (j-11); myt = clampT(loadI(sub_tf, k, f64)); off = WS_TF + k*H; }
      slot_off[tid] = off;
    }
  } else {
    if (tid < M*11) {
      int m = tid / 11, j = tid - m*11, sg = s0 + m;
      mym = m;
      int off;
      if (j == 0) { myt = clampT(loadI(lenp, sg, f64)); off = (e==1 ? WS_AEMB : WS_FEMB) + sg*H; }
      else {
        int k = sg*10 + (j-1);
        if (e == 1) { myt = clampT(loadI(sub_an, k, f64)); off = WS_AN + k*H; }
        else        { myt = clampT(loadI(sub_fa, k, f64)); off = WS_FA + k*H; }
      }
      slot_off[tid] = off;
    }
  }
  __syncthreads();

  float cc = 0.f;                 // c-state for my cell (seq=quad, col)
  // ---- hoisted loop-invariant addresses
  const int rdchunk = quad*4 + (lo & 3);
  const _Float16* rdb[2] = { &afr[0][0][rdchunk][0], &afr[1][0][rdchunk][0] };
  const int wrkt    = w >> 1;
  const int wrchunk = ((w & 1)*2 + (lo >> 3))*4 + quad;
  const int wrj     = lo & 7;
  _Float16* wrb[2] = { &afr[0][wrkt][wrchunk][wrj], &afr[1][wrkt][wrchunk][wrj] };
  const int c0 = 2*lane;
  const int snap_base = (c0 >> 5)*128 + ((c0 >> 3) & 3)*32 + (c0 & 7);  // + m*8

  // one LSTM step: read h' from buffer rp, write h(t+1) into buffer wp.
  // xa = (x[s0].x, x[s0].y, x[s1].x, x[s1].y), xb likewise for s2, s3.
  auto step = [&](int rp, int wp, int t, f32x4 xa, f32x4 xb) {
    const _Float16* rb = rdb[rp];
    half8 A[4];
    #pragma unroll
    for (int kt = 0; kt < 4; ++kt)
      A[kt] = *(const half8*)(rb + kt*128);

    // C-init: accumulator starts at xq[q][r] = b[q] + Wih[q]·x_t[seq r]
    // (rows r ≡ seq mod 4 under duplication; executes in the A-read shadow)
    f32x4 G[4];
    #pragma unroll
    for (int q = 0; q < 4; ++q) {
      G[q][0] = __builtin_fmaf(wx0[q], xa[0], __builtin_fmaf(wx1[q], xa[1], bb[q]));
      G[q][1] = __builtin_fmaf(wx0[q], xa[2], __builtin_fmaf(wx1[q], xa[3], bb[q]));
      G[q][2] = __builtin_fmaf(wx0[q], xb[0], __builtin_fmaf(wx1[q], xb[1], bb[q]));
      G[q][3] = __builtin_fmaf(wx0[q], xb[2], __builtin_fmaf(wx1[q], xb[3], bb[q]));
    }
    // interleaved chains; inner order (1,0,2,3): f-gate completes first,
    // o-gate last (off the serial c-chain)
    #pragma unroll
    for (int kt = 0; kt < 4; ++kt) {
      G[1] = __builtin_amdgcn_mfma_f32_16x16x32_f16(A[kt], Bf[1][kt], G[1], 0, 0, 0);
      G[0] = __builtin_amdgcn_mfma_f32_16x16x32_f16(A[kt], Bf[0][kt], G[0], 0, 0, 0);
      G[2] = __builtin_amdgcn_mfma_f32_16x16x32_f16(A[kt], Bf[2][kt], G[2], 0, 0, 0);
      G[3] = __builtin_amdgcn_mfma_f32_16x16x32_f16(A[kt], Bf[3][kt], G[3], 0, 0, 0);
    }

    float sf = sigmY(qsel(G[1], quad));
    float si = sigmY(qsel(G[0], quad));
    float tg = tanhY(qsel(G[2], quad));
    cc = sf*cc + si*tg;
    float tc = tanhY(cc * LOG2E2);
    float so = sigmY(qsel(G[3], quad));
    *wrb[wp] = (_Float16)(so * tc);
    __syncthreads();
    // ---- ballot-cooperative watcher snapshots -> LDS staging
    unsigned long long mask = __ballot(myt == t);
    if (mask) {
      const _Float16* sb = &afr[wp][0][0][0];
      do {
        int src = __ffsll((unsigned long long)mask) - 1;
        mask &= mask - 1;
        int m    = __shfl(mym, src);
        int slot = w*64 + src;
        unsigned int pk = *(const unsigned int*)(sb + snap_base + m*8);
        *(unsigned int*)&sbuf[slot][c0] = pk;
      } while (mask);
    }
  };

  #pragma unroll 1
  for (int t = 0; t < T; t += 2) {
    // both steps' x loaded up front (read-only LDS, safe across the barrier)
    f32x4 xa0 = *(const f32x4*)&xbf[t][0];
    f32x4 xb0 = *(const f32x4*)&xbf[t][2];
    f32x4 xa1 = *(const f32x4*)&xbf[t+1][0];
    f32x4 xb1 = *(const f32x4*)&xbf[t+1][2];
    step(0, 1, t,   xa0, xb0);
    step(1, 0, t+1, xa1, xb1);
  }

  __syncthreads();
  // ---- bulk snapshot write-out: slots * 64 dwords, coalesced
  for (int i = tid; i < nslots*64; i += 512) {
    int slot = i >> 6, c2 = i & 63;
    unsigned int pk = *(const unsigned int*)&sbuf[slot][2*c2];
    float2 v;
    v.x = (float)__builtin_bit_cast(_Float16, (unsigned short)(pk & 0xFFFFu));
    v.y = (float)__builtin_bit_cast(_Float16, (unsigned short)(pk >> 16));
    *(float2*)(ws + slot_off[slot] + 2*c2) = v;
  }
}

__global__ void dists(const float* __restrict__ ws, void* __restrict__ outv) {
  const int fbf = ((const int*)(ws + WS_FLAGS))[0];
  const int gtid = blockIdx.x*256 + threadIdx.x;
  const int widx = gtid >> 6, lane = gtid & 63;
  const float *pa, *pb;
  if (widx < 220)       { pa = ws + WS_TEMB + (size_t)widx*H;        pb = ws + WS_AEMB + (size_t)widx*H; }
  else if (widx < 440)  { int b = widx-220;  pa = ws + WS_TEMB + (size_t)b*H; pb = ws + WS_FEMB + (size_t)b*H; }
  else if (widx < 2640) { int k = widx-440;  pa = ws + WS_TA + (size_t)k*H;   pb = ws + WS_AN + (size_t)k*H; }
  else                  { int k = widx-2640; pa = ws + WS_TF + (size_t)k*H;   pb = ws + WS_FA + (size_t)k*H; }
  float d0 = pa[lane]    - pb[lane];
  float d1 = pa[lane+64] - pb[lane+64];
  float s  = scrub(d0*d0 + d1*d1);
  #pragma unroll
  for (int off = 32; off > 0; off >>= 1) s += __shfl_down(s, off, 64);
  if (lane == 0) {
    float r = __expf(-sqrtf(s));
    if (fbf) ((unsigned short*)outv)[widx] = f2bf(r);
    else     ((float*)outv)[widx] = r;
  }
}

extern "C" void kernel_launch(void* const* d_in, const int* in_sizes, int n_in,
                              void* d_out, int out_size, void* d_ws, size_t ws_size,
                              hipStream_t stream) {
  float* ws = (float*)d_ws;
  hipLaunchKernelGGL(lstm_scan, dim3(NBLK, 3), dim3(512), 0, stream,
                     d_in[0], d_in[1], d_in[2], d_in[3],
                     d_in[4], d_in[5], d_in[6],
                     d_in[7], d_in[8], d_in[9],
                     d_in[10], d_in[11], d_in[12], d_in[13], ws);
  hipLaunchKernelGGL(dists, dim3(4840*64/256), dim3(256), 0, stream, ws, d_out);
}

// Round 11
// 365.842 us; speedup vs baseline: 1.1311x; 1.1311x over previous
//
#include <hip/hip_runtime.h>

#define H    128
#define T    512
#define DX   4
#define BB   220
#define SAMP 10
#define NS   (BB*SAMP)
#define M    4        // sequences per block (220 = 55*4, no tail)
#define NBLK 55       // 220/4
#define MAXSLOT 84    // max watcher slots per block (e==0: M*21)

typedef _Float16 half8 __attribute__((ext_vector_type(8)));
typedef float    f32x4 __attribute__((ext_vector_type(4)));

// workspace layout (fp32 elements)
#define WS_TEMB 0
#define WS_AEMB (WS_TEMB + BB*H)
#define WS_FEMB (WS_AEMB + BB*H)
#define WS_TA   (WS_FEMB + BB*H)
#define WS_TF   (WS_TA + NS*H)
#define WS_AN   (WS_TF + NS*H)
#define WS_FA   (WS_AN + NS*H)
#define WS_FLAGS (WS_FA + NS*H)   // 2 ints: [0]=floats-are-bf16, [1]=ints-are-int64

#define LOG2E  1.442695041f
#define LOG2E2 2.885390082f

__device__ static inline float bf2f(unsigned short u) {
  unsigned int i = ((unsigned int)u) << 16;
  return __builtin_bit_cast(float, i);
}
__device__ static inline unsigned short f2bf(float f) {
  unsigned int i = __builtin_bit_cast(unsigned int, f);
  i += 0x7fffu + ((i >> 16) & 1u);
  return (unsigned short)(i >> 16);
}
__device__ static inline float loadF(const void* p, size_t i, int isbf) {
  return isbf ? bf2f(((const unsigned short*)p)[i]) : ((const float*)p)[i];
}
__device__ static inline int loadI(const void* p, int i, int is64) {
  return is64 ? (int)((const unsigned int*)p)[2*(size_t)i] : ((const int*)p)[i];
}
__device__ static inline float frcp(float x) { return __builtin_amdgcn_rcpf(x); }
__device__ static inline float ex2(float x)  { return __builtin_amdgcn_exp2f(x); }
// args pre-scaled by log2e (sigm) / 2*log2e (tanh)
__device__ static inline float sigmY(float y)  { return frcp(1.f + ex2(-y)); }
__device__ static inline float tanhY(float y)  { return 1.f - 2.f*frcp(1.f + ex2(y)); }
__device__ static inline float scrub(float x) { return (x == x) ? x : 0.f; }
__device__ static inline int clampT(int v) { v = v - 1; if (v < 0) v = 0; if (v > T-1) v = T-1; return v; }
// A rows 4-15 duplicate rows 0-3 => G[r] = gate[seq r][col] in every quad
__device__ static inline float qsel(f32x4 G, int quad) {
  float g01 = (quad & 1) ? G[1] : G[0];
  float g23 = (quad & 1) ? G[3] : G[2];
  return (quad & 2) ? g23 : g01;
}

__global__ __launch_bounds__(512, 2) void lstm_scan(
    const void* __restrict__ x0_, const void* __restrict__ len0,
    const void* __restrict__ sub_ta, const void* __restrict__ sub_tf,
    const void* __restrict__ x1_, const void* __restrict__ len1,
    const void* __restrict__ sub_an,
    const void* __restrict__ x2_, const void* __restrict__ len2,
    const void* __restrict__ sub_fa,
    const void* __restrict__ Wih, const void* __restrict__ Whh,
    const void* __restrict__ bih, const void* __restrict__ bhh,
    float* __restrict__ ws)
{
  const int e      = blockIdx.y;
  const int s0     = blockIdx.x * M;
  const int tid    = threadIdx.x;
  const int lane   = tid & 63;
  const int w      = tid >> 6;     // wave 0..7, owns h-cols [16w,16w+16)
  const int lo     = lane & 15;
  const int quad   = lane >> 4;    // elementwise: my seq

  // ---- in-block dtype detection (uniform scalar loop; block (0,0) publishes for dists)
  int fbf, f64;
  {
    const unsigned int* wp = (const unsigned int*)Whh;
    int cnt = 0;
    for (int i = 0; i < 64; ++i) {
      unsigned int lo16 = wp[i] & 0xFFFFu;
      int ex = (int)((lo16 >> 7) & 0xFFu);
      cnt += (ex >= 100 && ex <= 130);
    }
    fbf = (cnt >= 40);
    const unsigned int* l = (const unsigned int*)len0;
    f64 = ((l[1] | l[3] | l[5] | l[7]) == 0u);
    if (blockIdx.x == 0 && blockIdx.y == 0 && tid == 0) {
      int* fo = (int*)(ws + WS_FLAGS); fo[0] = fbf; fo[1] = f64;
    }
  }

  const void* xin  = (e==0) ? x0_ : (e==1 ? x1_ : x2_);
  const void* lenp = (e==0) ? len0 : (e==1 ? len1 : len2);

  // h'(t) in MFMA-fragment-major order: [buf][ktile][chunk=quad'*4+seq][8 halves]
  __shared__ __align__(16) _Float16 afr[2][4][16][8];
  __shared__ __align__(16) float2 xbf[M][T+2];            // x pairs, stride T+2
  __shared__ __align__(16) _Float16 sbuf[MAXSLOT][H];     // watcher snapshots (f16)
  __shared__ int slot_off[MAXSLOT];                       // ws offset per slot

  ((unsigned int*)afr)[tid] = 0u;                         // zero both h buffers
  // ---- stage x[:, :, 0:2] to LDS as f32 pairs
  for (int i = tid; i < M*T; i += 512) {
    int m = i >> 9, t = i & (T-1);
    size_t base = ((size_t)(s0+m)*T + t) * DX;
    xbf[m][t] = make_float2(loadF(xin, base + 0, fbf), loadF(xin, base + 1, fbf));
  }
  // ---- weight B-fragments: W_hh only, K=128; pre-scaled (i,f,o: log2e; g: 2*log2e)
  half8 Bf[4][4];
  const int col = w*16 + lo;
  #pragma unroll
  for (int q = 0; q < 4; ++q) {
    const float sc = (q == 2) ? LOG2E2 : LOG2E;
    const int g = q*128 + col;
    #pragma unroll
    for (int kt = 0; kt < 4; ++kt) {
      #pragma unroll
      for (int j = 0; j < 8; ++j) {
        const int k = kt*32 + quad*8 + j;
        Bf[q][kt][j] = (_Float16)(sc * loadF(Whh, (size_t)g*H + k, fbf));
      }
    }
  }
  // ---- per-lane x-weights and bias for my cell (seq=quad, col)
  float wx0[4], wx1[4], bb[4];
  #pragma unroll
  for (int q = 0; q < 4; ++q) {
    const float sc = (q == 2) ? LOG2E2 : LOG2E;
    const int g = q*128 + col;
    wx0[q] = sc * loadF(Wih, (size_t)g*2 + 0, fbf);
    wx1[q] = sc * loadF(Wih, (size_t)g*2 + 1, fbf);
    bb[q]  = sc * (loadF(bih, g, fbf) + loadF(bhh, g, fbf));
  }
  // ---- per-thread watcher slot (slot id == tid; max 84 < 512)
  const int nslots = (e == 0) ? M*21 : M*11;
  int myt = -1, mym = 0;
  if (e == 0) {
    if (tid < M*21) {
      int m = tid / 21, j = tid - m*21, sg = s0 + m;
      mym = m;
      int off;
      if (j == 0)       { myt = clampT(loadI(lenp, sg, f64));            off = WS_TEMB + sg*H; }
      else if (j <= 10) { int k = sg*10 + (j-1);  myt = clampT(loadI(sub_ta, k, f64)); off = WS_TA + k*H; }
      else              { int k = sg*10 + (j-11); myt = clampT(loadI(sub_tf, k, f64)); off = WS_TF + k*H; }
      slot_off[tid] = off;
    }
  } else {
    if (tid < M*11) {
      int m = tid / 11, j = tid - m*11, sg = s0 + m;
      mym = m;
      int off;
      if (j == 0) { myt = clampT(loadI(lenp, sg, f64)); off = (e==1 ? WS_AEMB : WS_FEMB) + sg*H; }
      else {
        int k = sg*10 + (j-1);
        if (e == 1) { myt = clampT(loadI(sub_an, k, f64)); off = WS_AN + k*H; }
        else        { myt = clampT(loadI(sub_fa, k, f64)); off = WS_FA + k*H; }
      }
      slot_off[tid] = off;
    }
  }
  __syncthreads();

  float cs = 0.f;                 // c-state in scaled domain: cs = c * 2log2e
  // ---- hoisted loop-invariant addresses
  const int rdchunk = quad*4 + (lo & 3);
  const _Float16* rdb[2] = { &afr[0][0][rdchunk][0], &afr[1][0][rdchunk][0] };
  const int wrkt    = w >> 1;
  const int wrchunk = ((w & 1)*2 + (lo >> 3))*4 + quad;
  const int wrj     = lo & 7;
  _Float16* wrb[2] = { &afr[0][wrkt][wrchunk][wrj], &afr[1][wrkt][wrchunk][wrj] };
  const float2* xrow = &xbf[quad][0];
  const int c0 = 2*lane;
  const int snap_base = (c0 >> 5)*128 + ((c0 >> 3) & 3)*32 + (c0 & 7);  // + m*8

  // one LSTM step: read h' from buffer rp, write h(t+1) into buffer wp
  auto step = [&](int rp, int wp, int t) {
    float2 xv = xrow[t];
    const _Float16* rb = rdb[rp];
    half8 A[4];
    #pragma unroll
    for (int kt = 0; kt < 4; ++kt)
      A[kt] = *(const half8*)(rb + kt*128);

    f32x4 G[4];
    #pragma unroll
    for (int q = 0; q < 4; ++q) G[q] = (f32x4){0.f, 0.f, 0.f, 0.f};
    #pragma unroll
    for (int kt = 0; kt < 4; ++kt)      // interleaved: 4 independent acc chains
      #pragma unroll
      for (int q = 0; q < 4; ++q)
        G[q] = __builtin_amdgcn_mfma_f32_16x16x32_f16(A[kt], Bf[q][kt], G[q], 0, 0, 0);

    float R[4];
    #pragma unroll
    for (int q = 0; q < 4; ++q)
      R[q] = qsel(G[q], quad) + bb[q] + wx0[q]*xv.x + wx1[q]*xv.y;

    float sf = sigmY(R[1]);
    float si = sigmY(R[0]);
    float tg = tanhY(R[2]);
    float ig = (si * tg) * LOG2E2;          // off-chain product, pre-scaled
    cs = sf*cs + ig;                         // serial chain: fma only
    float tc = tanhY(cs);                    // no mul on chain
    float so = sigmY(R[3]);                  // hides under the cs->tanh chain
    *wrb[wp] = (_Float16)(so * tc);
    __syncthreads();
    // ---- ballot-cooperative watcher snapshots -> LDS staging
    unsigned long long mask = __ballot(myt == t);
    if (mask) {
      const _Float16* sb = &afr[wp][0][0][0];
      do {
        int src = __ffsll((unsigned long long)mask) - 1;
        mask &= mask - 1;
        int m    = __shfl(mym, src);
        int slot = w*64 + src;
        unsigned int pk = *(const unsigned int*)(sb + snap_base + m*8);
        *(unsigned int*)&sbuf[slot][c0] = pk;
      } while (mask);
    }
  };

  #pragma unroll 1
  for (int t = 0; t < T; t += 2) {
    step(0, 1, t);
    step(1, 0, t+1);
  }

  __syncthreads();
  // ---- bulk snapshot write-out: slots * 64 dwords, coalesced
  for (int i = tid; i < nslots*64; i += 512) {
    int slot = i >> 6, c2 = i & 63;
    unsigned int pk = *(const unsigned int*)&sbuf[slot][2*c2];
    float2 v;
    v.x = (float)__builtin_bit_cast(_Float16, (unsigned short)(pk & 0xFFFFu));
    v.y = (float)__builtin_bit_cast(_Float16, (unsigned short)(pk >> 16));
    *(float2*)(ws + slot_off[slot] + 2*c2) = v;
  }
}

__global__ void dists(const float* __restrict__ ws, void* __restrict__ outv) {
  const int fbf = ((const int*)(ws + WS_FLAGS))[0];
  const int gtid = blockIdx.x*256 + threadIdx.x;
  const int widx = gtid >> 6, lane = gtid & 63;
  const float *pa, *pb;
  if (widx < 220)       { pa = ws + WS_TEMB + (size_t)widx*H;        pb = ws + WS_AEMB + (size_t)widx*H; }
  else if (widx < 440)  { int b = widx-220;  pa = ws + WS_TEMB + (size_t)b*H; pb = ws + WS_FEMB + (size_t)b*H; }
  else if (widx < 2640) { int k = widx-440;  pa = ws + WS_TA + (size_t)k*H;   pb = ws + WS_AN + (size_t)k*H; }
  else                  { int k = widx-2640; pa = ws + WS_TF + (size_t)k*H;   pb = ws + WS_FA + (size_t)k*H; }
  float d0 = pa[lane]    - pb[lane];
  float d1 = pa[lane+64] - pb[lane+64];
  float s  = scrub(d0*d0 + d1*d1);
  #pragma unroll
  for (int off = 32; off > 0; off >>= 1) s += __shfl_down(s, off, 64);
  if (lane == 0) {
    float r = __expf(-sqrtf(s));
    if (fbf) ((unsigned short*)outv)[widx] = f2bf(r);
    else     ((float*)outv)[widx] = r;
  }
}

extern "C" void kernel_launch(void* const* d_in, const int* in_sizes, int n_in,
                              void* d_out, int out_size, void* d_ws, size_t ws_size,
                              hipStream_t stream) {
  float* ws = (float*)d_ws;
  hipLaunchKernelGGL(lstm_scan, dim3(NBLK, 3), dim3(512), 0, stream,
                     d_in[0], d_in[1], d_in[2], d_in[3],
                     d_in[4], d_in[5], d_in[6],
                     d_in[7], d_in[8], d_in[9],
                     d_in[10], d_in[11], d_in[12], d_in[13], ws);
  hipLaunchKernelGGL(dists, dim3(4840*64/256), dim3(256), 0, stream, ws, d_out);
}